// Round 1
// baseline (355.241 us; speedup 1.0000x reference)
//
#include <hip/hip_runtime.h>
#include <stdint.h>

#define BB 8192
#define DD 128
#define MARGIN 1.0f

typedef __attribute__((ext_vector_type(8))) short short8_t;
typedef __attribute__((ext_vector_type(4))) float f32x4;

__device__ __forceinline__ unsigned fkey(float f) {
  unsigned u = __float_as_uint(f);
  return (u & 0x80000000u) ? ~u : (u | 0x80000000u);
}
__device__ __forceinline__ float finv(unsigned k) {
  return (k & 0x80000000u) ? __uint_as_float(k & 0x7fffffffu)
                           : __uint_as_float(~k);
}
__device__ __forceinline__ unsigned short f2bf(float f) {
  unsigned u = __float_as_uint(f);
  u = (u + 0x7fffu + ((u >> 16) & 1u)) >> 16;  // RNE
  return (unsigned short)u;
}

// ---------------- Kernel 0: bf16 convert + sqnorm + init ----------------
__global__ void prep_kernel(const float* __restrict__ E, unsigned short* __restrict__ Ebf,
                            float* __restrict__ sq, unsigned* __restrict__ tminu,
                            float* __restrict__ tot, int* __restrict__ cnt) {
  int wid = threadIdx.x >> 6, lane = threadIdx.x & 63;
  int row = blockIdx.x * 4 + wid;
  const float2 v = *(const float2*)(E + (size_t)row * DD + lane * 2);
  ushort2 bb;
  bb.x = f2bf(v.x);
  bb.y = f2bf(v.y);
  *(ushort2*)(Ebf + (size_t)row * DD + lane * 2) = bb;
  float s = v.x * v.x + v.y * v.y;
  for (int off = 1; off < 64; off <<= 1) s += __shfl_xor(s, off);
  if (lane == 0) {
    sq[row] = s;
    tminu[row] = 0xFFFFFFFFu;
  }
  if (blockIdx.x == 0 && threadIdx.x == 0) {
    *tot = 0.0f;
    *cnt = 0;
  }
}

// ---------------- Kernel 1: masked-min distance GEMM ----------------
// tile 128x128, 4 waves (2x2 of 64x64), K=128 in one shot.
// tracks t[i] = min over j (label_j != label_i) of (0.5*sq_j - dot(e_i, e_j))
__global__ __launch_bounds__(256, 2) void dist_min_kernel(
    const unsigned short* __restrict__ Ebf, const float* __restrict__ sq,
    const int* __restrict__ lab, unsigned* __restrict__ tminu) {
  __shared__ __align__(16) char ldsA[128 * 256];
  __shared__ __align__(16) char ldsB[128 * 256];
  __shared__ int labI[128];
  __shared__ int labJ[128];
  __shared__ float hJ[128];

  const int tid = threadIdx.x;
  const int bi = blockIdx.x >> 6, bj = blockIdx.x & 63;
  const int rI = bi * 128, rJ = bj * 128;

  // stage both 128x128 bf16 blocks with XOR swizzle (T2): byte ^= (row&7)<<4
  for (int q = tid; q < 2048; q += 256) {
    int r = q >> 4, c = q & 15;
    int dst = r * 256 + ((c * 16) ^ ((r & 7) << 4));
    *(float4*)(ldsA + dst) = *(const float4*)(Ebf + (size_t)(rI + r) * DD + c * 8);
    *(float4*)(ldsB + dst) = *(const float4*)(Ebf + (size_t)(rJ + r) * DD + c * 8);
  }
  if (tid < 128) {
    labI[tid] = lab[rI + tid];
    labJ[tid] = lab[rJ + tid];
    hJ[tid] = 0.5f * sq[rJ + tid];
  }
  __syncthreads();

  const int wid = tid >> 6, lane = tid & 63;
  const int wr = wid >> 1, wc = wid & 1;
  const int rowbase = wr * 64, colbase = wc * 64;
  const int cl = lane & 15, rg = lane >> 4;

  f32x4 acc[4][4];
#pragma unroll
  for (int m = 0; m < 4; m++)
#pragma unroll
    for (int n = 0; n < 4; n++) acc[m][n] = (f32x4){0.f, 0.f, 0.f, 0.f};

#pragma unroll
  for (int kk = 0; kk < 4; kk++) {
    const int kb = kk * 64 + rg * 16;  // byte offset of this lane's 16B k-chunk
    short8_t a[4], b[4];
#pragma unroll
    for (int m = 0; m < 4; m++) {
      int row = rowbase + m * 16 + cl;
      a[m] = *(const short8_t*)(ldsA + row * 256 + (kb ^ ((row & 7) << 4)));
    }
#pragma unroll
    for (int n = 0; n < 4; n++) {
      int row = colbase + n * 16 + cl;
      b[n] = *(const short8_t*)(ldsB + row * 256 + (kb ^ ((row & 7) << 4)));
    }
#pragma unroll
    for (int m = 0; m < 4; m++)
#pragma unroll
      for (int n = 0; n < 4; n++)
        acc[m][n] = __builtin_amdgcn_mfma_f32_16x16x32_bf16(a[m], b[n], acc[m][n], 0, 0, 0);
  }

  // epilogue: masked running min of (hJ[j] - dot)
  int jl[4];
  float jh[4];
#pragma unroll
  for (int n = 0; n < 4; n++) {
    int j = colbase + n * 16 + cl;
    jl[n] = labJ[j];
    jh[n] = hJ[j];
  }
  int il[4][4];
  float tm[4][4];
#pragma unroll
  for (int m = 0; m < 4; m++)
#pragma unroll
    for (int r = 0; r < 4; r++) {
      il[m][r] = labI[rowbase + m * 16 + rg * 4 + r];
      tm[m][r] = __builtin_huge_valf();
    }
#pragma unroll
  for (int m = 0; m < 4; m++)
#pragma unroll
    for (int n = 0; n < 4; n++) {
      f32x4 v = acc[m][n];
#pragma unroll
      for (int r = 0; r < 4; r++) {
        float t = jh[n] - v[r];
        if (il[m][r] != jl[n]) tm[m][r] = fminf(tm[m][r], t);
      }
    }
  // reduce across the 16 lanes (cl = 0..15) that share the same rows
#pragma unroll
  for (int m = 0; m < 4; m++)
#pragma unroll
    for (int r = 0; r < 4; r++) {
      float t = tm[m][r];
      t = fminf(t, __shfl_xor(t, 1));
      t = fminf(t, __shfl_xor(t, 2));
      t = fminf(t, __shfl_xor(t, 4));
      t = fminf(t, __shfl_xor(t, 8));
      tm[m][r] = t;
    }
  if (cl == 0) {
#pragma unroll
    for (int m = 0; m < 4; m++)
#pragma unroll
      for (int r = 0; r < 4; r++) {
        int row = rI + rowbase + m * 16 + rg * 4 + r;
        atomicMin(&tminu[row], fkey(tm[m][r]));
      }
  }
}

// ---------------- Kernel 2: positive pairs, exact fp32, loss accumulation ----------------
#define MAXQ 256
__global__ void pos_loss_kernel(const float* __restrict__ E, const int* __restrict__ lab,
                                const float* __restrict__ sq, const unsigned* __restrict__ tminu,
                                float* __restrict__ tot, int* __restrict__ cnt) {
  __shared__ int q[4][MAXQ];
  __shared__ int qn[4];
  const int tid = threadIdx.x, wid = tid >> 6, lane = tid & 63;
  if (tid < 4) qn[tid] = 0;
  __syncthreads();
  const int i = blockIdx.x * 4 + wid;
  const int labi = lab[i];
  const float2 ei = *(const float2*)(E + (size_t)i * DD + lane * 2);
  for (int j = lane; j < BB; j += 64) {
    if (lab[j] == labi && j != i) {
      int s = atomicAdd(&qn[wid], 1);
      if (s < MAXQ) q[wid][s] = j;
    }
  }
  __syncthreads();
  const float sqi = sq[i];
  const float hn = fmaxf(sqi + 2.0f * finv(tminu[i]), 0.0f);  // relu(min raw d)
  int n = qn[wid];
  if (n > MAXQ) n = MAXQ;
  float tsum = 0.0f;
  int tcnt = 0;
  for (int s = 0; s < n; s++) {
    int j = q[wid][s];
    float2 ej = *(const float2*)(E + (size_t)j * DD + lane * 2);
    float p = ei.x * ej.x + ei.y * ej.y;
    for (int off = 1; off < 64; off <<= 1) p += __shfl_xor(p, off);
    float d = fmaxf(sqi + sq[j] - 2.0f * p, 0.0f);
    if (hn < d) {
      tcnt++;
      tsum += d - hn + MARGIN;
    }
  }
  if (lane == 0 && tcnt) {
    atomicAdd(tot, tsum);
    atomicAdd(cnt, tcnt);
  }
}

// ---------------- Kernel 3: finalize ----------------
__global__ void finalize_kernel(const float* __restrict__ tot, const int* __restrict__ cnt,
                                float* __restrict__ out) {
  int c = *cnt;
  float t = *tot;
  out[0] = t / (float)(c > 0 ? c : 1);
  out[1] = (float)c;
}

extern "C" void kernel_launch(void* const* d_in, const int* in_sizes, int n_in,
                              void* d_out, int out_size, void* d_ws, size_t ws_size,
                              hipStream_t stream) {
  const float* E = (const float*)d_in[0];
  const int* lab = (const int*)d_in[1];
  float* out = (float*)d_out;

  char* ws = (char*)d_ws;
  unsigned short* Ebf = (unsigned short*)ws;                    // 2 MB
  float* sq = (float*)(ws + (size_t)BB * DD * 2);               // 32 KB
  unsigned* tminu = (unsigned*)((char*)sq + BB * 4);            // 32 KB
  float* tot = (float*)((char*)tminu + BB * 4);                 // 4 B
  int* cnt = (int*)((char*)tot + 4);                            // 4 B

  prep_kernel<<<BB / 4, 256, 0, stream>>>(E, Ebf, sq, tminu, tot, cnt);
  dist_min_kernel<<<(BB / 128) * (BB / 128), 256, 0, stream>>>(Ebf, sq, lab, tminu);
  pos_loss_kernel<<<BB / 4, 256, 0, stream>>>(E, lab, sq, tminu, tot, cnt);
  finalize_kernel<<<1, 1, 0, stream>>>(tot, cnt, out);
}

// Round 2
// 350.247 us; speedup vs baseline: 1.0143x; 1.0143x over previous
//
#include <hip/hip_runtime.h>
#include <stdint.h>

#define BB 8192
#define DD 128
#define MARGIN 1.0f
#define CCAP 48

typedef __attribute__((ext_vector_type(8))) short short8_t;
typedef __attribute__((ext_vector_type(4))) float f32x4;

__device__ __forceinline__ unsigned fkey(float f) {
  unsigned u = __float_as_uint(f);
  return (u & 0x80000000u) ? ~u : (u | 0x80000000u);
}
__device__ __forceinline__ float finv(unsigned k) {
  return (k & 0x80000000u) ? __uint_as_float(k & 0x7fffffffu)
                           : __uint_as_float(~k);
}
__device__ __forceinline__ unsigned short f2bf(float f) {
  unsigned u = __float_as_uint(f);
  u = (u + 0x7fffu + ((u >> 16) & 1u)) >> 16;  // RNE
  return (unsigned short)u;
}

// ---------------- Kernel 0: bf16 convert + sqnorm + bucket + init ----------------
__global__ void prep_kernel(const float* __restrict__ E, const int* __restrict__ lab,
                            unsigned short* __restrict__ Ebf,
                            float* __restrict__ sq, unsigned* __restrict__ tminu,
                            int* __restrict__ cls_cnt, int* __restrict__ cls_idx,
                            float* __restrict__ tot, int* __restrict__ cnt) {
  int wid = threadIdx.x >> 6, lane = threadIdx.x & 63;
  int row = blockIdx.x * 4 + wid;
  const float2 v = *(const float2*)(E + (size_t)row * DD + lane * 2);
  ushort2 bb;
  bb.x = f2bf(v.x);
  bb.y = f2bf(v.y);
  *(ushort2*)(Ebf + (size_t)row * DD + lane * 2) = bb;
  float s = v.x * v.x + v.y * v.y;
  for (int off = 1; off < 64; off <<= 1) s += __shfl_xor(s, off);
  if (lane == 0) {
    sq[row] = s;
    tminu[row] = 0xFFFFFFFFu;
    int labi = lab[row];
    int p = atomicAdd(&cls_cnt[labi], 1);
    if (p < CCAP) cls_idx[labi * CCAP + p] = row;
  }
  if (blockIdx.x == 0 && threadIdx.x == 0) {
    *tot = 0.0f;
    *cnt = 0;
  }
}

// ---------------- Kernel 1: masked-min distance GEMM ----------------
// tile 128x128, 4 waves (2x2 of 64x64), K=128 in one shot.
// tracks t[i] = min over j (label_j != label_i) of (0.5*sq_j - dot(e_i, e_j))
__global__ __launch_bounds__(256, 2) void dist_min_kernel(
    const unsigned short* __restrict__ Ebf, const float* __restrict__ sq,
    const int* __restrict__ lab, unsigned* __restrict__ tminu) {
  __shared__ __align__(16) char ldsA[128 * 256];
  __shared__ __align__(16) char ldsB[128 * 256];
  __shared__ int labI[128];
  __shared__ int labJ[128];
  __shared__ float hJ[128];

  const int tid = threadIdx.x;
  const int bi = blockIdx.x >> 6, bj = blockIdx.x & 63;
  const int rI = bi * 128, rJ = bj * 128;

  // stage both 128x128 bf16 blocks with XOR swizzle (T2): byte ^= (row&7)<<4
  for (int q = tid; q < 2048; q += 256) {
    int r = q >> 4, c = q & 15;
    int dst = r * 256 + ((c * 16) ^ ((r & 7) << 4));
    *(float4*)(ldsA + dst) = *(const float4*)(Ebf + (size_t)(rI + r) * DD + c * 8);
    *(float4*)(ldsB + dst) = *(const float4*)(Ebf + (size_t)(rJ + r) * DD + c * 8);
  }
  if (tid < 128) {
    labI[tid] = lab[rI + tid];
    labJ[tid] = lab[rJ + tid];
    hJ[tid] = 0.5f * sq[rJ + tid];
  }
  __syncthreads();

  const int wid = tid >> 6, lane = tid & 63;
  const int wr = wid >> 1, wc = wid & 1;
  const int rowbase = wr * 64, colbase = wc * 64;
  const int cl = lane & 15, rg = lane >> 4;

  f32x4 acc[4][4];
#pragma unroll
  for (int m = 0; m < 4; m++)
#pragma unroll
    for (int n = 0; n < 4; n++) acc[m][n] = (f32x4){0.f, 0.f, 0.f, 0.f};

#pragma unroll
  for (int kk = 0; kk < 4; kk++) {
    const int kb = kk * 64 + rg * 16;  // byte offset of this lane's 16B k-chunk
    short8_t a[4], b[4];
#pragma unroll
    for (int m = 0; m < 4; m++) {
      int row = rowbase + m * 16 + cl;
      a[m] = *(const short8_t*)(ldsA + row * 256 + (kb ^ ((row & 7) << 4)));
    }
#pragma unroll
    for (int n = 0; n < 4; n++) {
      int row = colbase + n * 16 + cl;
      b[n] = *(const short8_t*)(ldsB + row * 256 + (kb ^ ((row & 7) << 4)));
    }
#pragma unroll
    for (int m = 0; m < 4; m++)
#pragma unroll
      for (int n = 0; n < 4; n++)
        acc[m][n] = __builtin_amdgcn_mfma_f32_16x16x32_bf16(a[m], b[n], acc[m][n], 0, 0, 0);
  }

  // epilogue: masked running min of (hJ[j] - dot)
  int jl[4];
  float jh[4];
#pragma unroll
  for (int n = 0; n < 4; n++) {
    int j = colbase + n * 16 + cl;
    jl[n] = labJ[j];
    jh[n] = hJ[j];
  }
  int il[4][4];
  float tm[4][4];
#pragma unroll
  for (int m = 0; m < 4; m++)
#pragma unroll
    for (int r = 0; r < 4; r++) {
      il[m][r] = labI[rowbase + m * 16 + rg * 4 + r];
      tm[m][r] = __builtin_huge_valf();
    }
#pragma unroll
  for (int m = 0; m < 4; m++)
#pragma unroll
    for (int n = 0; n < 4; n++) {
      f32x4 v = acc[m][n];
#pragma unroll
      for (int r = 0; r < 4; r++) {
        float t = jh[n] - v[r];
        if (il[m][r] != jl[n]) tm[m][r] = fminf(tm[m][r], t);
      }
    }
  // reduce across the 16 lanes (cl = 0..15) that share the same rows
#pragma unroll
  for (int m = 0; m < 4; m++)
#pragma unroll
    for (int r = 0; r < 4; r++) {
      float t = tm[m][r];
      t = fminf(t, __shfl_xor(t, 1));
      t = fminf(t, __shfl_xor(t, 2));
      t = fminf(t, __shfl_xor(t, 4));
      t = fminf(t, __shfl_xor(t, 8));
      tm[m][r] = t;
    }
  if (cl == 0) {
#pragma unroll
    for (int m = 0; m < 4; m++)
#pragma unroll
      for (int r = 0; r < 4; r++) {
        int row = rI + rowbase + m * 16 + rg * 4 + r;
        atomicMin(&tminu[row], fkey(tm[m][r]));
      }
  }
}

// ---------------- Kernel 2: positive pairs via class buckets, exact fp32 ----------------
__global__ void pos_loss_kernel(const float* __restrict__ E, const int* __restrict__ lab,
                                const float* __restrict__ sq, const unsigned* __restrict__ tminu,
                                const int* __restrict__ cls_cnt, const int* __restrict__ cls_idx,
                                float* __restrict__ tot, int* __restrict__ cnt) {
  const int tid = threadIdx.x, wid = tid >> 6, lane = tid & 63;
  const int i = blockIdx.x * 4 + wid;
  const int labi = lab[i];
  int n = cls_cnt[labi];
  if (n > CCAP) n = CCAP;
  const float2 ei = *(const float2*)(E + (size_t)i * DD + lane * 2);
  const float sqi = sq[i];
  const float hn = fmaxf(sqi + 2.0f * finv(tminu[i]), 0.0f);  // relu(min raw d)
  float tsum = 0.0f;
  int tcnt = 0;
  for (int s = 0; s < n; s++) {
    int j = cls_idx[labi * CCAP + s];
    if (j == i) continue;
    float2 ej = *(const float2*)(E + (size_t)j * DD + lane * 2);
    float p = ei.x * ej.x + ei.y * ej.y;
    for (int off = 1; off < 64; off <<= 1) p += __shfl_xor(p, off);
    float d = fmaxf(sqi + sq[j] - 2.0f * p, 0.0f);
    if (hn < d) {
      tcnt++;
      tsum += d - hn + MARGIN;
    }
  }
  if (lane == 0 && tcnt) {
    atomicAdd(tot, tsum);
    atomicAdd(cnt, tcnt);
  }
}

// ---------------- Kernel 3: finalize ----------------
__global__ void finalize_kernel(const float* __restrict__ tot, const int* __restrict__ cnt,
                                float* __restrict__ out) {
  int c = *cnt;
  float t = *tot;
  out[0] = t / (float)(c > 0 ? c : 1);
  out[1] = (float)c;
}

extern "C" void kernel_launch(void* const* d_in, const int* in_sizes, int n_in,
                              void* d_out, int out_size, void* d_ws, size_t ws_size,
                              hipStream_t stream) {
  const float* E = (const float*)d_in[0];
  const int* lab = (const int*)d_in[1];
  float* out = (float*)d_out;

  char* ws = (char*)d_ws;
  unsigned short* Ebf = (unsigned short*)ws;                       // 2 MB
  float* sq = (float*)(ws + (size_t)BB * DD * 2);                  // 32 KB
  unsigned* tminu = (unsigned*)((char*)sq + BB * 4);               // 32 KB
  float* tot = (float*)((char*)tminu + BB * 4);                    // 4 B
  int* cnt = (int*)((char*)tot + 4);                               // 4 B
  int* cls_cnt = (int*)((char*)cnt + 4);                           // 4 KB (zeroed)
  int* cls_idx = (int*)((char*)cls_cnt + 1024 * 4);                // 192 KB

  hipMemsetAsync(cls_cnt, 0, 1024 * 4, stream);
  prep_kernel<<<BB / 4, 256, 0, stream>>>(E, lab, Ebf, sq, tminu, cls_cnt, cls_idx, tot, cnt);
  dist_min_kernel<<<(BB / 128) * (BB / 128), 256, 0, stream>>>(Ebf, sq, lab, tminu);
  pos_loss_kernel<<<BB / 4, 256, 0, stream>>>(E, lab, sq, tminu, cls_cnt, cls_idx, tot, cnt);
  finalize_kernel<<<1, 1, 0, stream>>>(tot, cnt, out);
}

// Round 4
// 159.258 us; speedup vs baseline: 2.2306x; 2.1992x over previous
//
#include <hip/hip_runtime.h>
#include <stdint.h>

#define BB 8192
#define DD 128
#define MARGIN 1.0f
#define CCAP 48
#define NBLK_POS (BB / 4)

typedef __attribute__((ext_vector_type(8))) short short8_t;
typedef __attribute__((ext_vector_type(4))) float f32x4;

__device__ __forceinline__ unsigned fkey(float f) {
  unsigned u = __float_as_uint(f);
  return (u & 0x80000000u) ? ~u : (u | 0x80000000u);
}
__device__ __forceinline__ float finv(unsigned k) {
  return (k & 0x80000000u) ? __uint_as_float(k & 0x7fffffffu)
                           : __uint_as_float(~k);
}
__device__ __forceinline__ unsigned short f2bf(float f) {
  unsigned u = __float_as_uint(f);
  u = (u + 0x7fffu + ((u >> 16) & 1u)) >> 16;  // RNE
  return (unsigned short)u;
}

// ---------------- Kernel 0: bf16 convert + sqnorm + bucket + init ----------------
__global__ void prep_kernel(const float* __restrict__ E, const int* __restrict__ lab,
                            unsigned short* __restrict__ Ebf,
                            float* __restrict__ sq, unsigned* __restrict__ tminu,
                            int* __restrict__ cls_cnt, int* __restrict__ cls_idx) {
  int wid = threadIdx.x >> 6, lane = threadIdx.x & 63;
  int row = blockIdx.x * 4 + wid;
  const float2 v = *(const float2*)(E + (size_t)row * DD + lane * 2);
  ushort2 bb;
  bb.x = f2bf(v.x);
  bb.y = f2bf(v.y);
  *(ushort2*)(Ebf + (size_t)row * DD + lane * 2) = bb;
  float s = v.x * v.x + v.y * v.y;
  for (int off = 1; off < 64; off <<= 1) s += __shfl_xor(s, off);
  if (lane == 0) {
    sq[row] = s;
    tminu[row] = 0xFFFFFFFFu;
    int labi = lab[row];
    int p = atomicAdd(&cls_cnt[labi], 1);
    if (p < CCAP) cls_idx[labi * CCAP + p] = row;
  }
}

// ---------------- Kernel 1: masked-min distance GEMM ----------------
// tile 128x128, 4 waves (2x2 of 64x64), K=128 in one shot.
// tracks t[i] = min over j (label_j != label_i) of (0.5*sq_j - dot(e_i, e_j))
__global__ __launch_bounds__(256, 2) void dist_min_kernel(
    const unsigned short* __restrict__ Ebf, const float* __restrict__ sq,
    const int* __restrict__ lab, unsigned* __restrict__ tminu) {
  __shared__ __align__(16) char ldsA[128 * 256];
  __shared__ __align__(16) char ldsB[128 * 256];
  __shared__ int labI[128];
  __shared__ int labJ[128];
  __shared__ float hJ[128];

  const int tid = threadIdx.x;
  const int bi = blockIdx.x >> 6, bj = blockIdx.x & 63;
  const int rI = bi * 128, rJ = bj * 128;

  // stage both 128x128 bf16 blocks with XOR swizzle (T2): byte ^= (row&7)<<4
  for (int q = tid; q < 2048; q += 256) {
    int r = q >> 4, c = q & 15;
    int dst = r * 256 + ((c * 16) ^ ((r & 7) << 4));
    *(float4*)(ldsA + dst) = *(const float4*)(Ebf + (size_t)(rI + r) * DD + c * 8);
    *(float4*)(ldsB + dst) = *(const float4*)(Ebf + (size_t)(rJ + r) * DD + c * 8);
  }
  if (tid < 128) {
    labI[tid] = lab[rI + tid];
    labJ[tid] = lab[rJ + tid];
    hJ[tid] = 0.5f * sq[rJ + tid];
  }
  __syncthreads();

  const int wid = tid >> 6, lane = tid & 63;
  const int wr = wid >> 1, wc = wid & 1;
  const int rowbase = wr * 64, colbase = wc * 64;
  const int cl = lane & 15, rg = lane >> 4;

  f32x4 acc[4][4];
#pragma unroll
  for (int m = 0; m < 4; m++)
#pragma unroll
    for (int n = 0; n < 4; n++) acc[m][n] = (f32x4){0.f, 0.f, 0.f, 0.f};

#pragma unroll
  for (int kk = 0; kk < 4; kk++) {
    const int kb = kk * 64 + rg * 16;  // byte offset of this lane's 16B k-chunk
    short8_t a[4], b[4];
#pragma unroll
    for (int m = 0; m < 4; m++) {
      int row = rowbase + m * 16 + cl;
      a[m] = *(const short8_t*)(ldsA + row * 256 + (kb ^ ((row & 7) << 4)));
    }
#pragma unroll
    for (int n = 0; n < 4; n++) {
      int row = colbase + n * 16 + cl;
      b[n] = *(const short8_t*)(ldsB + row * 256 + (kb ^ ((row & 7) << 4)));
    }
#pragma unroll
    for (int m = 0; m < 4; m++)
#pragma unroll
      for (int n = 0; n < 4; n++)
        acc[m][n] = __builtin_amdgcn_mfma_f32_16x16x32_bf16(a[m], b[n], acc[m][n], 0, 0, 0);
  }

  // epilogue: masked running min of (hJ[j] - dot)
  int jl[4];
  float jh[4];
#pragma unroll
  for (int n = 0; n < 4; n++) {
    int j = colbase + n * 16 + cl;
    jl[n] = labJ[j];
    jh[n] = hJ[j];
  }
  int il[4][4];
  float tm[4][4];
#pragma unroll
  for (int m = 0; m < 4; m++)
#pragma unroll
    for (int r = 0; r < 4; r++) {
      il[m][r] = labI[rowbase + m * 16 + rg * 4 + r];
      tm[m][r] = __builtin_huge_valf();
    }
#pragma unroll
  for (int m = 0; m < 4; m++)
#pragma unroll
    for (int n = 0; n < 4; n++) {
      f32x4 v = acc[m][n];
#pragma unroll
      for (int r = 0; r < 4; r++) {
        float t = jh[n] - v[r];
        if (il[m][r] != jl[n]) tm[m][r] = fminf(tm[m][r], t);
      }
    }
  // reduce across the 16 lanes (cl = 0..15) that share the same rows
#pragma unroll
  for (int m = 0; m < 4; m++)
#pragma unroll
    for (int r = 0; r < 4; r++) {
      float t = tm[m][r];
      t = fminf(t, __shfl_xor(t, 1));
      t = fminf(t, __shfl_xor(t, 2));
      t = fminf(t, __shfl_xor(t, 4));
      t = fminf(t, __shfl_xor(t, 8));
      tm[m][r] = t;
    }
  if (cl == 0) {
#pragma unroll
    for (int m = 0; m < 4; m++)
#pragma unroll
      for (int r = 0; r < 4; r++) {
        int row = rI + rowbase + m * 16 + rg * 4 + r;
        atomicMin(&tminu[row], fkey(tm[m][r]));
      }
  }
}

// ---------------- Kernel 2: positive pairs via class buckets, exact fp32 ----------------
// NO global atomics: per-block partials, reduced in finalize_kernel.
__global__ void pos_loss_kernel(const float* __restrict__ E, const int* __restrict__ lab,
                                const float* __restrict__ sq, const unsigned* __restrict__ tminu,
                                const int* __restrict__ cls_cnt, const int* __restrict__ cls_idx,
                                float* __restrict__ ptot, int* __restrict__ pcnt) {
  __shared__ float stot[4];
  __shared__ int scnt[4];
  const int tid = threadIdx.x, wid = tid >> 6, lane = tid & 63;
  const int i = blockIdx.x * 4 + wid;
  const int labi = lab[i];
  int n = cls_cnt[labi];
  if (n > CCAP) n = CCAP;
  const float2 ei = *(const float2*)(E + (size_t)i * DD + lane * 2);
  const float sqi = sq[i];
  const float hn = fmaxf(sqi + 2.0f * finv(tminu[i]), 0.0f);  // relu(min raw d)
  float tsum = 0.0f;
  int tcnt = 0;
  for (int s = 0; s < n; s++) {
    int j = cls_idx[labi * CCAP + s];
    if (j == i) continue;
    float2 ej = *(const float2*)(E + (size_t)j * DD + lane * 2);
    float p = ei.x * ej.x + ei.y * ej.y;
    for (int off = 1; off < 64; off <<= 1) p += __shfl_xor(p, off);
    float d = fmaxf(sqi + sq[j] - 2.0f * p, 0.0f);
    if (hn < d) {
      tcnt++;
      tsum += d - hn + MARGIN;
    }
  }
  // all lanes hold identical tsum/tcnt (butterfly); reduce across 4 waves via LDS
  if (lane == 0) {
    stot[wid] = tsum;
    scnt[wid] = tcnt;
  }
  __syncthreads();
  if (tid == 0) {
    ptot[blockIdx.x] = stot[0] + stot[1] + stot[2] + stot[3];
    pcnt[blockIdx.x] = scnt[0] + scnt[1] + scnt[2] + scnt[3];
  }
}

// ---------------- Kernel 3: reduce partials + finalize ----------------
__global__ void finalize_kernel(const float* __restrict__ ptot, const int* __restrict__ pcnt,
                                float* __restrict__ out) {
  __shared__ float stot[4];
  __shared__ int scnt[4];
  const int tid = threadIdx.x, wid = tid >> 6, lane = tid & 63;
  float t = 0.0f;
  int c = 0;
  for (int k = tid; k < NBLK_POS; k += 256) {
    t += ptot[k];
    c += pcnt[k];
  }
  for (int off = 1; off < 64; off <<= 1) {
    t += __shfl_xor(t, off);
    c += __shfl_xor(c, off);
  }
  if (lane == 0) {
    stot[wid] = t;
    scnt[wid] = c;
  }
  __syncthreads();
  if (tid == 0) {
    float tt = stot[0] + stot[1] + stot[2] + stot[3];
    int cc = scnt[0] + scnt[1] + scnt[2] + scnt[3];
    out[0] = tt / (float)(cc > 0 ? cc : 1);
    out[1] = (float)cc;
  }
}

extern "C" void kernel_launch(void* const* d_in, const int* in_sizes, int n_in,
                              void* d_out, int out_size, void* d_ws, size_t ws_size,
                              hipStream_t stream) {
  const float* E = (const float*)d_in[0];
  const int* lab = (const int*)d_in[1];
  float* out = (float*)d_out;

  char* ws = (char*)d_ws;
  unsigned short* Ebf = (unsigned short*)ws;                       // 2 MB
  float* sq = (float*)(ws + (size_t)BB * DD * 2);                  // 32 KB
  unsigned* tminu = (unsigned*)((char*)sq + BB * 4);               // 32 KB
  int* cls_cnt = (int*)((char*)tminu + BB * 4);                    // 4 KB (zeroed)
  int* cls_idx = (int*)((char*)cls_cnt + 1024 * 4);                // 192 KB
  float* ptot = (float*)((char*)cls_idx + 1024 * CCAP * 4);        // 8 KB
  int* pcnt = (int*)((char*)ptot + NBLK_POS * 4);                  // 8 KB

  hipMemsetAsync(cls_cnt, 0, 1024 * 4, stream);
  prep_kernel<<<BB / 4, 256, 0, stream>>>(E, lab, Ebf, sq, tminu, cls_cnt, cls_idx);
  dist_min_kernel<<<(BB / 128) * (BB / 128), 256, 0, stream>>>(Ebf, sq, lab, tminu);
  pos_loss_kernel<<<NBLK_POS, 256, 0, stream>>>(E, lab, sq, tminu, cls_cnt, cls_idx, ptot, pcnt);
  finalize_kernel<<<1, 256, 0, stream>>>(ptot, pcnt, out);
}

// Round 5
// 133.396 us; speedup vs baseline: 2.6631x; 1.1939x over previous
//
#include <hip/hip_runtime.h>
#include <stdint.h>

#define BB 8192
#define DD 128
#define MARGIN 1.0f
#define CCAP 48
#define NBLK_POS (BB / 4)
#define NT 64                       // 8192/128 tile blocks per dim
#define NTRI (NT * (NT + 1) / 2)    // 2080 triangular tiles

typedef __attribute__((ext_vector_type(8))) short short8_t;
typedef __attribute__((ext_vector_type(4))) float f32x4;

__device__ __forceinline__ unsigned fkey(float f) {
  unsigned u = __float_as_uint(f);
  return (u & 0x80000000u) ? ~u : (u | 0x80000000u);
}
__device__ __forceinline__ float finv(unsigned k) {
  return (k & 0x80000000u) ? __uint_as_float(k & 0x7fffffffu)
                           : __uint_as_float(~k);
}
__device__ __forceinline__ unsigned short f2bf(float f) {
  unsigned u = __float_as_uint(f);
  u = (u + 0x7fffu + ((u >> 16) & 1u)) >> 16;  // RNE
  return (unsigned short)u;
}

// ---------------- Kernel 0: bf16 convert + sqnorm + bucket + init ----------------
__global__ void prep_kernel(const float* __restrict__ E, const int* __restrict__ lab,
                            unsigned short* __restrict__ Ebf,
                            float* __restrict__ sq, unsigned* __restrict__ tminu,
                            int* __restrict__ cls_cnt, int* __restrict__ cls_idx) {
  int wid = threadIdx.x >> 6, lane = threadIdx.x & 63;
  int row = blockIdx.x * 4 + wid;
  const float2 v = *(const float2*)(E + (size_t)row * DD + lane * 2);
  ushort2 bb;
  bb.x = f2bf(v.x);
  bb.y = f2bf(v.y);
  *(ushort2*)(Ebf + (size_t)row * DD + lane * 2) = bb;
  float s = v.x * v.x + v.y * v.y;
  for (int off = 1; off < 64; off <<= 1) s += __shfl_xor(s, off);
  if (lane == 0) {
    sq[row] = s;
    tminu[row] = 0xFFFFFFFFu;
    int labi = lab[row];
    int p = atomicAdd(&cls_cnt[labi], 1);
    if (p < CCAP) cls_idx[labi * CCAP + p] = row;
  }
}

// ---------------- Kernel 1: masked-min distance GEMM, triangular tiles ----------------
// Tile (bi<=bj): computes dot block I x J once; updates BOTH
//   row-side: tminu[i] <- min(0.5*sq_j - dot)  over j with lab_j != lab_i
//   col-side: tminu[j] <- min(0.5*sq_i - dot)  over i with lab_i != lab_j
// A (I-tile) staged in LDS (XOR-swizzled); B (J-tile) fragments loaded
// directly from global (L2/L3-resident) before the staging barrier.
__global__ __launch_bounds__(256) void dist_min_kernel(
    const unsigned short* __restrict__ Ebf, const float* __restrict__ sq,
    const int* __restrict__ lab, unsigned* __restrict__ tminu) {
  __shared__ __align__(16) char ldsA[128 * 256];
  __shared__ int labI[128];
  __shared__ int labJ[128];
  __shared__ float hI[128];
  __shared__ float hJ[128];

  const int tid = threadIdx.x;

  // triangular decode: row_start(b) = b*NT - b*(b-1)/2
  int idx = blockIdx.x;
  int bi = (int)((129.0f - sqrtf(16641.0f - 8.0f * (float)idx)) * 0.5f);
  if (bi < 0) bi = 0;
  if (bi > NT - 1) bi = NT - 1;
  while (bi > 0 && bi * NT - bi * (bi - 1) / 2 > idx) bi--;
  while (bi < NT - 1 && (bi + 1) * NT - (bi + 1) * bi / 2 <= idx) bi++;
  const int bj = bi + (idx - (bi * NT - bi * (bi - 1) / 2));
  const int rI = bi * 128, rJ = bj * 128;

  const int wid = tid >> 6, lane = tid & 63;
  const int wr = wid >> 1, wc = wid & 1;
  const int rowbase = wr * 64, colbase = wc * 64;
  const int cl = lane & 15, rg = lane >> 4;

  // B fragments straight from global: row = rJ+colbase+n*16+cl, bytes [kk*64+rg*16, +16)
  short8_t bfrag[4][4];
#pragma unroll
  for (int n = 0; n < 4; n++) {
    const char* rowp = (const char*)Ebf + (size_t)(rJ + colbase + n * 16 + cl) * 256 + rg * 16;
#pragma unroll
    for (int kk = 0; kk < 4; kk++)
      bfrag[n][kk] = *(const short8_t*)(rowp + kk * 64);
  }

  // stage A (I-tile) with XOR swizzle: byte ^= (row&7)<<4
  for (int q = tid; q < 2048; q += 256) {
    int r = q >> 4, c = q & 15;
    int dst = r * 256 + ((c * 16) ^ ((r & 7) << 4));
    *(float4*)(ldsA + dst) = *(const float4*)(Ebf + (size_t)(rI + r) * DD + c * 8);
  }
  if (tid < 128) {
    labI[tid] = lab[rI + tid];
    hI[tid] = 0.5f * sq[rI + tid];
  } else {
    int t2 = tid - 128;
    labJ[t2] = lab[rJ + t2];
    hJ[t2] = 0.5f * sq[rJ + t2];
  }
  __syncthreads();

  f32x4 acc[4][4];
#pragma unroll
  for (int m = 0; m < 4; m++)
#pragma unroll
    for (int n = 0; n < 4; n++) acc[m][n] = (f32x4){0.f, 0.f, 0.f, 0.f};

#pragma unroll
  for (int kk = 0; kk < 4; kk++) {
    const int kb = kk * 64 + rg * 16;
    short8_t a[4];
#pragma unroll
    for (int m = 0; m < 4; m++) {
      int row = rowbase + m * 16 + cl;
      a[m] = *(const short8_t*)(ldsA + row * 256 + (kb ^ ((row & 7) << 4)));
    }
#pragma unroll
    for (int m = 0; m < 4; m++)
#pragma unroll
      for (int n = 0; n < 4; n++)
        acc[m][n] = __builtin_amdgcn_mfma_f32_16x16x32_bf16(a[m], bfrag[n][kk], acc[m][n], 0, 0, 0);
  }

  // ---- epilogue (loads scoped here to keep MFMA-phase VGPR pressure down) ----
  int jl[4];
  float jh[4];
#pragma unroll
  for (int n = 0; n < 4; n++) {
    int j = colbase + n * 16 + cl;
    jl[n] = labJ[j];
    jh[n] = hJ[j];
  }
  int il[4][4];
  float hi[4][4];
#pragma unroll
  for (int m = 0; m < 4; m++)
#pragma unroll
    for (int r = 0; r < 4; r++) {
      int i = rowbase + m * 16 + rg * 4 + r;
      il[m][r] = labI[i];
      hi[m][r] = hI[i];
    }

  // row-side min: t[i] = min_j (hJ[j] - dot)
  float tm[4][4];
#pragma unroll
  for (int m = 0; m < 4; m++)
#pragma unroll
    for (int r = 0; r < 4; r++) tm[m][r] = __builtin_huge_valf();
#pragma unroll
  for (int m = 0; m < 4; m++)
#pragma unroll
    for (int n = 0; n < 4; n++) {
      f32x4 v = acc[m][n];
#pragma unroll
      for (int r = 0; r < 4; r++) {
        float t = jh[n] - v[r];
        if (il[m][r] != jl[n]) tm[m][r] = fminf(tm[m][r], t);
      }
    }
#pragma unroll
  for (int m = 0; m < 4; m++)
#pragma unroll
    for (int r = 0; r < 4; r++) {
      float t = tm[m][r];
      t = fminf(t, __shfl_xor(t, 1));
      t = fminf(t, __shfl_xor(t, 2));
      t = fminf(t, __shfl_xor(t, 4));
      t = fminf(t, __shfl_xor(t, 8));
      tm[m][r] = t;
    }
  if (cl == 0) {
#pragma unroll
    for (int m = 0; m < 4; m++)
#pragma unroll
      for (int r = 0; r < 4; r++) {
        int row = rI + rowbase + m * 16 + rg * 4 + r;
        atomicMin(&tminu[row], fkey(tm[m][r]));
      }
  }

  // col-side min: t[j] = min_i (hI[i] - dot)
#pragma unroll
  for (int n = 0; n < 4; n++) {
    float cm = __builtin_huge_valf();
#pragma unroll
    for (int m = 0; m < 4; m++) {
      f32x4 v = acc[m][n];
#pragma unroll
      for (int r = 0; r < 4; r++) {
        float u = hi[m][r] - v[r];
        if (il[m][r] != jl[n]) cm = fminf(cm, u);
      }
    }
    cm = fminf(cm, __shfl_xor(cm, 16));
    cm = fminf(cm, __shfl_xor(cm, 32));
    if (rg == 0) atomicMin(&tminu[rJ + colbase + n * 16 + cl], fkey(cm));
  }
}

// ---------------- Kernel 2: positive pairs via class buckets, exact fp32 ----------------
__global__ void pos_loss_kernel(const float* __restrict__ E, const int* __restrict__ lab,
                                const float* __restrict__ sq, const unsigned* __restrict__ tminu,
                                const int* __restrict__ cls_cnt, const int* __restrict__ cls_idx,
                                float* __restrict__ ptot, int* __restrict__ pcnt) {
  __shared__ float stot[4];
  __shared__ int scnt[4];
  const int tid = threadIdx.x, wid = tid >> 6, lane = tid & 63;
  const int i = blockIdx.x * 4 + wid;
  const int labi = lab[i];
  int n = cls_cnt[labi];
  if (n > CCAP) n = CCAP;
  const float2 ei = *(const float2*)(E + (size_t)i * DD + lane * 2);
  const float sqi = sq[i];
  const float hn = fmaxf(sqi + 2.0f * finv(tminu[i]), 0.0f);  // relu(min raw d)
  float tsum = 0.0f;
  int tcnt = 0;
  for (int s = 0; s < n; s++) {
    int j = cls_idx[labi * CCAP + s];
    if (j == i) continue;
    float2 ej = *(const float2*)(E + (size_t)j * DD + lane * 2);
    float p = ei.x * ej.x + ei.y * ej.y;
    for (int off = 1; off < 64; off <<= 1) p += __shfl_xor(p, off);
    float d = fmaxf(sqi + sq[j] - 2.0f * p, 0.0f);
    if (hn < d) {
      tcnt++;
      tsum += d - hn + MARGIN;
    }
  }
  if (lane == 0) {
    stot[wid] = tsum;
    scnt[wid] = tcnt;
  }
  __syncthreads();
  if (tid == 0) {
    ptot[blockIdx.x] = stot[0] + stot[1] + stot[2] + stot[3];
    pcnt[blockIdx.x] = scnt[0] + scnt[1] + scnt[2] + scnt[3];
  }
}

// ---------------- Kernel 3: reduce partials + finalize ----------------
__global__ void finalize_kernel(const float* __restrict__ ptot, const int* __restrict__ pcnt,
                                float* __restrict__ out) {
  __shared__ float stot[4];
  __shared__ int scnt[4];
  const int tid = threadIdx.x, wid = tid >> 6, lane = tid & 63;
  float t = 0.0f;
  int c = 0;
  for (int k = tid; k < NBLK_POS; k += 256) {
    t += ptot[k];
    c += pcnt[k];
  }
  for (int off = 1; off < 64; off <<= 1) {
    t += __shfl_xor(t, off);
    c += __shfl_xor(c, off);
  }
  if (lane == 0) {
    stot[wid] = t;
    scnt[wid] = c;
  }
  __syncthreads();
  if (tid == 0) {
    float tt = stot[0] + stot[1] + stot[2] + stot[3];
    int cc = scnt[0] + scnt[1] + scnt[2] + scnt[3];
    out[0] = tt / (float)(cc > 0 ? cc : 1);
    out[1] = (float)cc;
  }
}

extern "C" void kernel_launch(void* const* d_in, const int* in_sizes, int n_in,
                              void* d_out, int out_size, void* d_ws, size_t ws_size,
                              hipStream_t stream) {
  const float* E = (const float*)d_in[0];
  const int* lab = (const int*)d_in[1];
  float* out = (float*)d_out;

  char* ws = (char*)d_ws;
  unsigned short* Ebf = (unsigned short*)ws;                       // 2 MB
  float* sq = (float*)(ws + (size_t)BB * DD * 2);                  // 32 KB
  unsigned* tminu = (unsigned*)((char*)sq + BB * 4);               // 32 KB
  int* cls_cnt = (int*)((char*)tminu + BB * 4);                    // 4 KB (zeroed)
  int* cls_idx = (int*)((char*)cls_cnt + 1024 * 4);                // 192 KB
  float* ptot = (float*)((char*)cls_idx + 1024 * CCAP * 4);        // 8 KB
  int* pcnt = (int*)((char*)ptot + NBLK_POS * 4);                  // 8 KB

  hipMemsetAsync(cls_cnt, 0, 1024 * 4, stream);
  prep_kernel<<<BB / 4, 256, 0, stream>>>(E, lab, Ebf, sq, tminu, cls_cnt, cls_idx);
  dist_min_kernel<<<NTRI, 256, 0, stream>>>(Ebf, sq, lab, tminu);
  pos_loss_kernel<<<NBLK_POS, 256, 0, stream>>>(E, lab, sq, tminu, cls_cnt, cls_idx, ptot, pcnt);
  finalize_kernel<<<1, 256, 0, stream>>>(ptot, pcnt, out);
}

// Round 6
// 129.432 us; speedup vs baseline: 2.7446x; 1.0306x over previous
//
#include <hip/hip_runtime.h>
#include <stdint.h>

#define BB 8192
#define DD 128
#define MARGIN 1.0f
#define CCAP 48
#define NBLK_POS (BB / 4)
#define NT 64            // 128-row/col tiles per dim
#define NCH 16           // chunks per panel
#define JTPC (NT / NCH)  // 4 J-tiles per chunk

typedef __attribute__((ext_vector_type(8))) short short8_t;
typedef __attribute__((ext_vector_type(4))) float f32x4;

__device__ __forceinline__ unsigned short f2bf(float f) {
  unsigned u = __float_as_uint(f);
  u = (u + 0x7fffu + ((u >> 16) & 1u)) >> 16;  // RNE
  return (unsigned short)u;
}

// ---------------- Kernel 0: bf16 convert + sqnorm + bucket ----------------
__global__ void prep_kernel(const float* __restrict__ E, const int* __restrict__ lab,
                            unsigned short* __restrict__ Ebf,
                            float* __restrict__ sq,
                            int* __restrict__ cls_cnt, int* __restrict__ cls_idx) {
  int wid = threadIdx.x >> 6, lane = threadIdx.x & 63;
  int row = blockIdx.x * 4 + wid;
  const float2 v = *(const float2*)(E + (size_t)row * DD + lane * 2);
  ushort2 bb;
  bb.x = f2bf(v.x);
  bb.y = f2bf(v.y);
  *(ushort2*)(Ebf + (size_t)row * DD + lane * 2) = bb;
  float s = v.x * v.x + v.y * v.y;
  for (int off = 1; off < 64; off <<= 1) s += __shfl_xor(s, off);
  if (lane == 0) {
    sq[row] = s;
    int labi = lab[row];
    int p = atomicAdd(&cls_cnt[labi], 1);
    if (p < CCAP) cls_idx[labi * CCAP + p] = row;
  }
}

// ---------------- Kernel 1: masked-min distance GEMM, panel x chunk ----------------
// Block (p,c): rows [p*128,+128), cols [c*512,+512) as 4 J-tiles.
// Keeps t[i] = min_j (0.5*sq_j - dot) with lab_j != lab_i in REGISTERS across
// the 4 tiles, then one cross-lane/cross-wave reduce and plain stores to
// part[c][row]. Zero atomics on the min path.
__global__ __launch_bounds__(256) void dist_min_kernel(
    const unsigned short* __restrict__ Ebf, const float* __restrict__ sq,
    const int* __restrict__ lab, float* __restrict__ part) {
  __shared__ __align__(16) char ldsA[128 * 256];
  __shared__ int labI[128];
  __shared__ float redMin[4][64];

  const int tid = threadIdx.x;
  const int p = blockIdx.x >> 4, c = blockIdx.x & (NCH - 1);
  const int rI = p * 128;

  // stage A (row-panel) with XOR swizzle: byte ^= (row&7)<<4
  for (int q = tid; q < 2048; q += 256) {
    int r = q >> 4, cc = q & 15;
    int dst = r * 256 + ((cc * 16) ^ ((r & 7) << 4));
    *(float4*)(ldsA + dst) = *(const float4*)(Ebf + (size_t)(rI + r) * DD + cc * 8);
  }
  if (tid < 128) labI[tid] = lab[rI + tid];
  __syncthreads();

  const int wid = tid >> 6, lane = tid & 63;
  const int wr = wid >> 1, wc = wid & 1;
  const int rowbase = wr * 64, colbase = wc * 64;
  const int cl = lane & 15, rg = lane >> 4;

  int il[4][4];
#pragma unroll
  for (int m = 0; m < 4; m++)
#pragma unroll
    for (int r = 0; r < 4; r++) il[m][r] = labI[rowbase + m * 16 + rg * 4 + r];

  float tm[4][4];
#pragma unroll
  for (int m = 0; m < 4; m++)
#pragma unroll
    for (int r = 0; r < 4; r++) tm[m][r] = __builtin_huge_valf();

#pragma unroll
  for (int t = 0; t < JTPC; t++) {
    const int rJ = (c * JTPC + t) * 128;

    // B fragments + labels + half-sqnorms straight from global (L2-hot)
    short8_t b[4][4];
    int jl[4];
    float jh[4];
#pragma unroll
    for (int n = 0; n < 4; n++) {
      const int j = rJ + colbase + n * 16 + cl;
      const char* rowp = (const char*)Ebf + (size_t)j * 256 + rg * 16;
#pragma unroll
      for (int kk = 0; kk < 4; kk++) b[n][kk] = *(const short8_t*)(rowp + kk * 64);
      jl[n] = lab[j];
      jh[n] = 0.5f * sq[j];
    }

    f32x4 acc[4][4];
#pragma unroll
    for (int m = 0; m < 4; m++)
#pragma unroll
      for (int n = 0; n < 4; n++) acc[m][n] = (f32x4){0.f, 0.f, 0.f, 0.f};

#pragma unroll
    for (int kk = 0; kk < 4; kk++) {
      const int kb = kk * 64 + rg * 16;
      short8_t a[4];
#pragma unroll
      for (int m = 0; m < 4; m++) {
        int row = rowbase + m * 16 + cl;
        a[m] = *(const short8_t*)(ldsA + row * 256 + (kb ^ ((row & 7) << 4)));
      }
#pragma unroll
      for (int m = 0; m < 4; m++)
#pragma unroll
        for (int n = 0; n < 4; n++)
          acc[m][n] = __builtin_amdgcn_mfma_f32_16x16x32_bf16(a[m], b[n][kk], acc[m][n], 0, 0, 0);
    }

    // register epilogue: masked running min, no shuffles
#pragma unroll
    for (int m = 0; m < 4; m++)
#pragma unroll
      for (int n = 0; n < 4; n++) {
        f32x4 v = acc[m][n];
#pragma unroll
        for (int r = 0; r < 4; r++) {
          float u = jh[n] - v[r];
          if (il[m][r] != jl[n]) tm[m][r] = fminf(tm[m][r], u);
        }
      }
  }

  // reduce across the 16 lanes sharing the same rows
#pragma unroll
  for (int m = 0; m < 4; m++)
#pragma unroll
    for (int r = 0; r < 4; r++) {
      float t = tm[m][r];
      t = fminf(t, __shfl_xor(t, 1));
      t = fminf(t, __shfl_xor(t, 2));
      t = fminf(t, __shfl_xor(t, 4));
      t = fminf(t, __shfl_xor(t, 8));
      tm[m][r] = t;
    }
  if (cl == 0) {
#pragma unroll
    for (int m = 0; m < 4; m++)
#pragma unroll
      for (int r = 0; r < 4; r++) redMin[wid][m * 16 + rg * 4 + r] = tm[m][r];
  }
  __syncthreads();
  // combine the two column-half waves, one plain store per row
  if (wc == 0) {
    float v = fminf(redMin[wid][lane], redMin[wid + 1][lane]);
    part[(size_t)c * BB + rI + rowbase + lane] = v;
  }
}

// ---------------- Kernel 1b: fold chunk partials ----------------
__global__ void reduce_min_kernel(const float* __restrict__ part, float* __restrict__ tmin) {
  const int row = blockIdx.x * 256 + threadIdx.x;
  float m = __builtin_huge_valf();
#pragma unroll
  for (int cch = 0; cch < NCH; cch++) m = fminf(m, part[(size_t)cch * BB + row]);
  tmin[row] = m;
}

// ---------------- Kernel 2: positive pairs via class buckets, exact fp32 ----------------
__global__ void pos_loss_kernel(const float* __restrict__ E, const int* __restrict__ lab,
                                const float* __restrict__ sq, const float* __restrict__ tmin,
                                const int* __restrict__ cls_cnt, const int* __restrict__ cls_idx,
                                float* __restrict__ ptot, int* __restrict__ pcnt) {
  __shared__ float stot[4];
  __shared__ int scnt[4];
  const int tid = threadIdx.x, wid = tid >> 6, lane = tid & 63;
  const int i = blockIdx.x * 4 + wid;
  const int labi = lab[i];
  int n = cls_cnt[labi];
  if (n > CCAP) n = CCAP;
  const float2 ei = *(const float2*)(E + (size_t)i * DD + lane * 2);
  const float sqi = sq[i];
  const float hn = fmaxf(sqi + 2.0f * tmin[i], 0.0f);  // relu(min raw d)
  float tsum = 0.0f;
  int tcnt = 0;
  for (int s = 0; s < n; s++) {
    int j = cls_idx[labi * CCAP + s];
    if (j == i) continue;
    float2 ej = *(const float2*)(E + (size_t)j * DD + lane * 2);
    float pp = ei.x * ej.x + ei.y * ej.y;
    for (int off = 1; off < 64; off <<= 1) pp += __shfl_xor(pp, off);
    float d = fmaxf(sqi + sq[j] - 2.0f * pp, 0.0f);
    if (hn < d) {
      tcnt++;
      tsum += d - hn + MARGIN;
    }
  }
  if (lane == 0) {
    stot[wid] = tsum;
    scnt[wid] = tcnt;
  }
  __syncthreads();
  if (tid == 0) {
    ptot[blockIdx.x] = stot[0] + stot[1] + stot[2] + stot[3];
    pcnt[blockIdx.x] = scnt[0] + scnt[1] + scnt[2] + scnt[3];
  }
}

// ---------------- Kernel 3: reduce partials + finalize ----------------
__global__ void finalize_kernel(const float* __restrict__ ptot, const int* __restrict__ pcnt,
                                float* __restrict__ out) {
  __shared__ float stot[4];
  __shared__ int scnt[4];
  const int tid = threadIdx.x, wid = tid >> 6, lane = tid & 63;
  float t = 0.0f;
  int c = 0;
  for (int k = tid; k < NBLK_POS; k += 256) {
    t += ptot[k];
    c += pcnt[k];
  }
  for (int off = 1; off < 64; off <<= 1) {
    t += __shfl_xor(t, off);
    c += __shfl_xor(c, off);
  }
  if (lane == 0) {
    stot[wid] = t;
    scnt[wid] = c;
  }
  __syncthreads();
  if (tid == 0) {
    float tt = stot[0] + stot[1] + stot[2] + stot[3];
    int cc = scnt[0] + scnt[1] + scnt[2] + scnt[3];
    out[0] = tt / (float)(cc > 0 ? cc : 1);
    out[1] = (float)cc;
  }
}

extern "C" void kernel_launch(void* const* d_in, const int* in_sizes, int n_in,
                              void* d_out, int out_size, void* d_ws, size_t ws_size,
                              hipStream_t stream) {
  const float* E = (const float*)d_in[0];
  const int* lab = (const int*)d_in[1];
  float* out = (float*)d_out;

  char* ws = (char*)d_ws;
  unsigned short* Ebf = (unsigned short*)ws;                       // 2 MB
  float* sq = (float*)(ws + (size_t)BB * DD * 2);                  // 32 KB
  float* tmin = (float*)((char*)sq + BB * 4);                      // 32 KB
  int* cls_cnt = (int*)((char*)tmin + BB * 4);                     // 4 KB (zeroed)
  int* cls_idx = (int*)((char*)cls_cnt + 1024 * 4);                // 192 KB
  float* ptot = (float*)((char*)cls_idx + 1024 * CCAP * 4);        // 8 KB
  int* pcnt = (int*)((char*)ptot + NBLK_POS * 4);                  // 8 KB
  float* part = (float*)((char*)pcnt + NBLK_POS * 4);              // 512 KB

  hipMemsetAsync(cls_cnt, 0, 1024 * 4, stream);
  prep_kernel<<<BB / 4, 256, 0, stream>>>(E, lab, Ebf, sq, cls_cnt, cls_idx);
  dist_min_kernel<<<NT * NCH, 256, 0, stream>>>(Ebf, sq, lab, part);
  reduce_min_kernel<<<BB / 256, 256, 0, stream>>>(part, tmin);
  pos_loss_kernel<<<NBLK_POS, 256, 0, stream>>>(E, lab, sq, tmin, cls_cnt, cls_idx, ptot, pcnt);
  finalize_kernel<<<1, 256, 0, stream>>>(ptot, pcnt, out);
}

// Round 7
// 110.508 us; speedup vs baseline: 3.2146x; 1.1712x over previous
//
#include <hip/hip_runtime.h>
#include <stdint.h>

#define BB 8192
#define DD 128
#define MARGIN 1.0f
#define CCAP 48
#define NBLK_POS (BB / 4)
#define NCH 8              // chunks (blocks) per row-panel
#define CHCOLS (BB / NCH)  // 1024 cols per chunk
#define TPC (CHCOLS / 64)  // 16 B-tiles of 64 cols

typedef __attribute__((ext_vector_type(8))) short short8_t;
typedef __attribute__((ext_vector_type(4))) float f32x4;

// async global->LDS, 16B per lane; LDS dest is wave-uniform base + lane*16
#define GLL16(g, l)                                                                   \
  __builtin_amdgcn_global_load_lds(                                                   \
      (const __attribute__((address_space(1))) unsigned int*)(g),                     \
      (__attribute__((address_space(3))) unsigned int*)(l), 16, 0, 0)

__device__ __forceinline__ unsigned short f2bf(float f) {
  unsigned u = __float_as_uint(f);
  u = (u + 0x7fffu + ((u >> 16) & 1u)) >> 16;  // RNE
  return (unsigned short)u;
}

// ---------------- Kernel 0: bf16 convert + sqnorm + bucket ----------------
__global__ void prep_kernel(const float* __restrict__ E, const int* __restrict__ lab,
                            unsigned short* __restrict__ Ebf,
                            float* __restrict__ sq,
                            int* __restrict__ cls_cnt, int* __restrict__ cls_idx) {
  int wid = threadIdx.x >> 6, lane = threadIdx.x & 63;
  int row = blockIdx.x * 4 + wid;
  const float2 v = *(const float2*)(E + (size_t)row * DD + lane * 2);
  ushort2 bb;
  bb.x = f2bf(v.x);
  bb.y = f2bf(v.y);
  *(ushort2*)(Ebf + (size_t)row * DD + lane * 2) = bb;
  float s = v.x * v.x + v.y * v.y;
  for (int off = 1; off < 64; off <<= 1) s += __shfl_xor(s, off);
  if (lane == 0) {
    sq[row] = s;
    int labi = lab[row];
    int p = atomicAdd(&cls_cnt[labi], 1);
    if (p < CCAP) cls_idx[labi * CCAP + p] = row;
  }
}

// ---------------- Kernel 1: masked-min distance GEMM ----------------
// Block (p,c): rows [p*128,+128) x cols [c*1024,+1024).
// A staged once in LDS via global_load_lds (inverse-swizzled source);
// B streamed as 16 x 64-col tiles, double-buffered, 2-phase pipeline:
//   STAGE(next) -> compute(cur) -> __syncthreads (drains vmcnt) -> swap.
// t[i] = min_j (0.5*sq_j - dot) masked lab_j != lab_i, kept in registers;
// plain stores to part[c][row]. No atomics.
__global__ __launch_bounds__(256) void dist_min_kernel(
    const unsigned short* __restrict__ Ebf, const float* __restrict__ sq,
    const int* __restrict__ lab, float* __restrict__ part) {
  __shared__ __align__(16) char ldsA[128 * 256];    // 32 KB, swizzled
  __shared__ __align__(16) char ldsB[2][64 * 256];  // 2 x 16 KB, swizzled
  __shared__ int labC[CHCOLS];
  __shared__ float hC[CHCOLS];
  __shared__ int labI[128];
  __shared__ float redMin[4][64];

  const int tid = threadIdx.x;
  const int p = blockIdx.x >> 3, c = blockIdx.x & (NCH - 1);
  const int rI = p * 128;
  const int cBase = c * CHCOLS;

  const int wid = tid >> 6, lane = tid & 63;
  const int l4 = lane >> 4, c16 = lane & 15;

  // ---- prologue staging (all async + plain LDS writes, one barrier) ----
  // A panel: wave wid stages rows [wid*32, +32); source chunk pre-swizzled
#pragma unroll
  for (int q = 0; q < 8; q++) {
    int r = wid * 32 + q * 4 + l4;
    int chunk = c16 ^ (r & 7);
    GLL16((const char*)Ebf + (size_t)(rI + r) * 256 + chunk * 16,
          ldsA + wid * 8192 + q * 1024);
  }
  // B tile 0: wave wid stages tile-rows [wid*16, +16)
#pragma unroll
  for (int q = 0; q < 4; q++) {
    int r = wid * 16 + q * 4 + l4;
    int chunk = c16 ^ (r & 7);
    GLL16((const char*)Ebf + (size_t)(cBase + r) * 256 + chunk * 16,
          ldsB[0] + wid * 4096 + q * 1024);
  }
  // column metadata for the whole chunk
  for (int q = tid; q < CHCOLS; q += 256) {
    labC[q] = lab[cBase + q];
    hC[q] = 0.5f * sq[cBase + q];
  }
  if (tid < 128) labI[tid] = lab[rI + tid];
  __syncthreads();  // drains vmcnt(0): A, B0, metadata all ready

  const int wr = wid >> 1, wc = wid & 1;
  const int rowbase = wr * 64;
  const int cl = c16, rg = l4;

  int il[4][4];
#pragma unroll
  for (int m = 0; m < 4; m++)
#pragma unroll
    for (int r = 0; r < 4; r++) il[m][r] = labI[rowbase + m * 16 + rg * 4 + r];

  float tm[4][4];
#pragma unroll
  for (int m = 0; m < 4; m++)
#pragma unroll
    for (int r = 0; r < 4; r++) tm[m][r] = __builtin_huge_valf();

  for (int t = 0; t < TPC; t++) {
    const int cur = t & 1;
    // stage next B tile into the other buffer (stays in flight through compute)
    if (t + 1 < TPC) {
#pragma unroll
      for (int q = 0; q < 4; q++) {
        int r = wid * 16 + q * 4 + l4;
        int chunk = c16 ^ (r & 7);
        GLL16((const char*)Ebf + (size_t)(cBase + (t + 1) * 64 + r) * 256 + chunk * 16,
              ldsB[cur ^ 1] + wid * 4096 + q * 1024);
      }
    }

    int jl[2];
    float jh[2];
#pragma unroll
    for (int n = 0; n < 2; n++) {
      int j = t * 64 + wc * 32 + n * 16 + cl;
      jl[n] = labC[j];
      jh[n] = hC[j];
    }

    f32x4 acc[4][2];
#pragma unroll
    for (int m = 0; m < 4; m++)
#pragma unroll
      for (int n = 0; n < 2; n++) acc[m][n] = (f32x4){0.f, 0.f, 0.f, 0.f};

#pragma unroll
    for (int kk = 0; kk < 4; kk++) {
      const int kb = kk * 64 + rg * 16;
      short8_t a[4], b[2];
#pragma unroll
      for (int m = 0; m < 4; m++) {
        int row = rowbase + m * 16 + cl;
        a[m] = *(const short8_t*)(ldsA + row * 256 + (kb ^ ((row & 7) << 4)));
      }
#pragma unroll
      for (int n = 0; n < 2; n++) {
        int row = wc * 32 + n * 16 + cl;
        b[n] = *(const short8_t*)(ldsB[cur] + row * 256 + (kb ^ ((row & 7) << 4)));
      }
#pragma unroll
      for (int m = 0; m < 4; m++)
#pragma unroll
        for (int n = 0; n < 2; n++)
          acc[m][n] = __builtin_amdgcn_mfma_f32_16x16x32_bf16(a[m], b[n], acc[m][n], 0, 0, 0);
    }

    // register fold: masked running min
#pragma unroll
    for (int m = 0; m < 4; m++)
#pragma unroll
      for (int n = 0; n < 2; n++) {
        f32x4 v = acc[m][n];
#pragma unroll
        for (int r = 0; r < 4; r++) {
          float u = jh[n] - v[r];
          if (il[m][r] != jl[n]) tm[m][r] = fminf(tm[m][r], u);
        }
      }

    __syncthreads();  // drains the in-flight STAGE; next tile ready, buffer reusable
  }

  // reduce across the 16 lanes sharing the same rows
#pragma unroll
  for (int m = 0; m < 4; m++)
#pragma unroll
    for (int r = 0; r < 4; r++) {
      float t = tm[m][r];
      t = fminf(t, __shfl_xor(t, 1));
      t = fminf(t, __shfl_xor(t, 2));
      t = fminf(t, __shfl_xor(t, 4));
      t = fminf(t, __shfl_xor(t, 8));
      tm[m][r] = t;
    }
  if (cl == 0) {
#pragma unroll
    for (int m = 0; m < 4; m++)
#pragma unroll
      for (int r = 0; r < 4; r++) redMin[wid][m * 16 + rg * 4 + r] = tm[m][r];
  }
  __syncthreads();
  if (wc == 0) {
    float v = fminf(redMin[wid][lane], redMin[wid + 1][lane]);
    part[(size_t)c * BB + rI + rowbase + lane] = v;
  }
}

// ---------------- Kernel 2: positives + hardest-neg fold, exact fp32 ----------------
__global__ void pos_loss_kernel(const float* __restrict__ E, const int* __restrict__ lab,
                                const float* __restrict__ sq, const float* __restrict__ part,
                                const int* __restrict__ cls_cnt, const int* __restrict__ cls_idx,
                                float* __restrict__ ptot, int* __restrict__ pcnt) {
  __shared__ float stot[4];
  __shared__ int scnt[4];
  const int tid = threadIdx.x, wid = tid >> 6, lane = tid & 63;
  const int i = blockIdx.x * 4 + wid;
  const int labi = lab[i];
  int n = cls_cnt[labi];
  if (n > CCAP) n = CCAP;
  const float2 ei = *(const float2*)(E + (size_t)i * DD + lane * 2);
  const float sqi = sq[i];
  float mn = __builtin_huge_valf();
#pragma unroll
  for (int cc = 0; cc < NCH; cc++) mn = fminf(mn, part[(size_t)cc * BB + i]);
  const float hn = fmaxf(sqi + 2.0f * mn, 0.0f);  // relu(min raw d)
  float tsum = 0.0f;
  int tcnt = 0;
  for (int s = 0; s < n; s++) {
    int j = cls_idx[labi * CCAP + s];
    if (j == i) continue;
    float2 ej = *(const float2*)(E + (size_t)j * DD + lane * 2);
    float pp = ei.x * ej.x + ei.y * ej.y;
    for (int off = 1; off < 64; off <<= 1) pp += __shfl_xor(pp, off);
    float d = fmaxf(sqi + sq[j] - 2.0f * pp, 0.0f);
    if (hn < d) {
      tcnt++;
      tsum += d - hn + MARGIN;
    }
  }
  if (lane == 0) {
    stot[wid] = tsum;
    scnt[wid] = tcnt;
  }
  __syncthreads();
  if (tid == 0) {
    ptot[blockIdx.x] = stot[0] + stot[1] + stot[2] + stot[3];
    pcnt[blockIdx.x] = scnt[0] + scnt[1] + scnt[2] + scnt[3];
  }
}

// ---------------- Kernel 3: reduce partials + finalize ----------------
__global__ void finalize_kernel(const float* __restrict__ ptot, const int* __restrict__ pcnt,
                                float* __restrict__ out) {
  __shared__ float stot[4];
  __shared__ int scnt[4];
  const int tid = threadIdx.x, wid = tid >> 6, lane = tid & 63;
  float t = 0.0f;
  int c = 0;
  for (int k = tid; k < NBLK_POS; k += 256) {
    t += ptot[k];
    c += pcnt[k];
  }
  for (int off = 1; off < 64; off <<= 1) {
    t += __shfl_xor(t, off);
    c += __shfl_xor(c, off);
  }
  if (lane == 0) {
    stot[wid] = t;
    scnt[wid] = c;
  }
  __syncthreads();
  if (tid == 0) {
    float tt = stot[0] + stot[1] + stot[2] + stot[3];
    int cc = scnt[0] + scnt[1] + scnt[2] + scnt[3];
    out[0] = tt / (float)(cc > 0 ? cc : 1);
    out[1] = (float)cc;
  }
}

extern "C" void kernel_launch(void* const* d_in, const int* in_sizes, int n_in,
                              void* d_out, int out_size, void* d_ws, size_t ws_size,
                              hipStream_t stream) {
  const float* E = (const float*)d_in[0];
  const int* lab = (const int*)d_in[1];
  float* out = (float*)d_out;

  char* ws = (char*)d_ws;
  unsigned short* Ebf = (unsigned short*)ws;                 // 2 MB
  float* sq = (float*)(ws + (size_t)BB * DD * 2);            // 32 KB
  int* cls_cnt = (int*)((char*)sq + BB * 4);                 // 4 KB (zeroed)
  int* cls_idx = (int*)((char*)cls_cnt + 1024 * 4);          // 192 KB
  float* ptot = (float*)((char*)cls_idx + 1024 * CCAP * 4);  // 8 KB
  int* pcnt = (int*)((char*)ptot + NBLK_POS * 4);            // 8 KB
  float* part = (float*)((char*)pcnt + NBLK_POS * 4);        // 256 KB

  hipMemsetAsync(cls_cnt, 0, 1024 * 4, stream);
  prep_kernel<<<BB / 4, 256, 0, stream>>>(E, lab, Ebf, sq, cls_cnt, cls_idx);
  dist_min_kernel<<<64 * NCH, 256, 0, stream>>>(Ebf, sq, lab, part);
  pos_loss_kernel<<<NBLK_POS, 256, 0, stream>>>(E, lab, sq, part, cls_cnt, cls_idx, ptot, pcnt);
  finalize_kernel<<<1, 256, 0, stream>>>(ptot, pcnt, out);
}